// Round 1
// baseline (221.212 us; speedup 1.0000x reference)
//
#include <hip/hip_runtime.h>

// Conv2d 7x7, stride 2, pad 3, 1x1 channels, 8192x8192 fp32 -> 4096x4096 fp32.
// LDS-tiled: 64x32 output tile per 256-thread block, 4x2 outputs per thread.
// XOR-swizzled LDS (chunk ^= (row>>2)&7) => conflict-free ds_read_b128.

#define THREADS 256
#define TILE_W 64
#define TILE_H 32
#define IN_H 69          // TILE_H*2 + 5
#define IN_W 133         // TILE_W*2 + 5
#define LDS_STRIDE 160   // floats per LDS row (40 16B-chunks; ^7 stays in-row)
#define IMG 8192
#define OUTW 4096

__global__ __launch_bounds__(THREADS)
void conv7x7_s2(const float* __restrict__ x, const float* __restrict__ wgt,
                const float* __restrict__ bias, float* __restrict__ out) {
  __shared__ __align__(16) float lds[IN_H * LDS_STRIDE];
  const int t = threadIdx.x;
  const int tile_x = blockIdx.x * TILE_W;
  const int tile_y = blockIdx.y * TILE_H;
  const int g0c = tile_x * 2 - 3;   // input col of LDS col 0 (can be <0: padding)
  const int g0r = tile_y * 2 - 3;   // input row of LDS row 0

  // weights (uniform address -> likely s_load; 49 regs worst case)
  float wv[49];
#pragma unroll
  for (int i = 0; i < 49; ++i) wv[i] = wgt[i];
  const float bv = bias[0];

  // ---- global -> LDS (swizzled write) ----
  {
    const int c0 = t & 31;
    const int r0 = t >> 5;
    for (int r = r0; r < IN_H; r += 8) {
      const int gr = g0r + r;
      const bool rok = (unsigned)gr < (unsigned)IMG;
      const float* rowp = x + (long long)gr * IMG;
      const int xr = (r >> 2) & 7;
#pragma unroll
      for (int cc = 0; cc < 5; ++cc) {
        const int c = c0 + cc * 32;
        if (c < IN_W) {
          const int gc = g0c + c;
          float v = 0.0f;
          if (rok && (unsigned)gc < (unsigned)IMG) v = rowp[gc];
          const int chunk = (c >> 2) ^ xr;
          lds[r * LDS_STRIDE + chunk * 4 + (c & 3)] = v;
        }
      }
    }
  }
  __syncthreads();

  // ---- compute: each thread 4 wide x 2 tall outputs ----
  const int tx = t & 15;
  const int ty = t >> 4;
  float acc[2][4];
#pragma unroll
  for (int y = 0; y < 2; ++y)
#pragma unroll
    for (int xx = 0; xx < 4; ++xx) acc[y][xx] = bv;

#pragma unroll
  for (int j = 0; j < 9; ++j) {
    const int li = 4 * ty + j;            // LDS input row
    const int xr = (li >> 2) & 7;
    float rbuf[16];
#pragma unroll
    for (int q = 0; q < 4; ++q) {
      const int chunk = (2 * tx + q) ^ xr;  // swizzled 16B chunk
      const float4 v =
          *reinterpret_cast<const float4*>(&lds[li * LDS_STRIDE + chunk * 4]);
      rbuf[4 * q + 0] = v.x;
      rbuf[4 * q + 1] = v.y;
      rbuf[4 * q + 2] = v.z;
      rbuf[4 * q + 3] = v.w;
    }
    // rbuf[i] = input col (8*tx + i) relative to tile; outputs use i = 2*xx+kw <= 12
#pragma unroll
    for (int y = 0; y < 2; ++y) {
      const int kh = j - 2 * y;           // compile-time after unroll
      if (kh >= 0 && kh <= 6) {
#pragma unroll
        for (int xx = 0; xx < 4; ++xx)
#pragma unroll
          for (int kw = 0; kw < 7; ++kw)
            acc[y][xx] = fmaf(rbuf[2 * xx + kw], wv[kh * 7 + kw], acc[y][xx]);
      }
    }
  }

  // ---- store: 2 x global_store_dwordx4, contiguous across tx ----
  const int ox = tile_x + 4 * tx;
  const int oy = tile_y + 2 * ty;
#pragma unroll
  for (int y = 0; y < 2; ++y) {
    float4 v = make_float4(acc[y][0], acc[y][1], acc[y][2], acc[y][3]);
    *reinterpret_cast<float4*>(&out[(long long)(oy + y) * OUTW + ox]) = v;
  }
}

extern "C" void kernel_launch(void* const* d_in, const int* in_sizes, int n_in,
                              void* d_out, int out_size, void* d_ws, size_t ws_size,
                              hipStream_t stream) {
  const float* x = (const float*)d_in[0];
  const float* w = (const float*)d_in[1];
  const float* b = (const float*)d_in[2];
  float* out = (float*)d_out;
  dim3 grid(OUTW / TILE_W, OUTW / TILE_H);  // 64 x 128
  conv7x7_s2<<<grid, dim3(THREADS), 0, stream>>>(x, w, b, out);
}

// Round 2
// 73.821 us; speedup vs baseline: 2.9966x; 2.9966x over previous
//
#include <hip/hip_runtime.h>

// Conv2d 7x7, stride 2, pad 3, 1ch, 8192x8192 fp32 -> 4096x4096 fp32.
// 64x32 output tile / 256-thread block, 4x2 outputs per thread.
// float4 staging from aligned base (tile_x*2-4); LDS 34 chunks/row (37.5KB
// -> 4 blocks/CU); XOR swizzle on chunks<32 => conflict-free ds_read_b128.

#define THREADS 256
#define TILE_W 64
#define TILE_H 32
#define IN_H 69            // TILE_H*2 + 5
#define CHUNKS 34          // float4 chunks per LDS row (covers 136 cols)
#define LDS_STRIDE (CHUNKS * 4)
#define NSLOT (IN_H * CHUNKS)   // 2346
#define IMG 8192
#define OUTW 4096

__global__ __launch_bounds__(THREADS, 4)
void conv7x7_s2(const float* __restrict__ x, const float* __restrict__ wgt,
                const float* __restrict__ bias, float* __restrict__ out) {
  __shared__ __align__(16) float lds[IN_H * LDS_STRIDE];
  const int t = threadIdx.x;
  const int tile_x = blockIdx.x * TILE_W;
  const int tile_y = blockIdx.y * TILE_H;
  const int g0c4 = tile_x * 2 - 4;  // ALIGNED input col of LDS col 0
  const int g0r = tile_y * 2 - 3;   // input row of LDS row 0

  float wv[49];
#pragma unroll
  for (int i = 0; i < 49; ++i) wv[i] = wgt[i];
  const float bv = bias[0];

  // ---- global -> LDS staging: float4 chunks, load-all then write-all ----
  // LDS chunk q of row r holds global chunk src = (q<32) ? q^xr : q.
  float4 vbuf[10];
  int laddr[10];
#pragma unroll
  for (int i = 0; i < 10; ++i) {
    const int s = t + THREADS * i;
    const bool ok = (s < NSLOT);
    const int r = s / CHUNKS;          // const-div -> mul_hi
    const int q = s - r * CHUNKS;
    const int xr = (r >> 2) & 7;
    const int src = (q < 32) ? (q ^ xr) : q;
    const int gr = g0r + r;
    const int gc = g0c4 + 4 * src;     // aligned; fully in or fully out
    float4 v = make_float4(0.f, 0.f, 0.f, 0.f);
    if (ok && (unsigned)gr < (unsigned)IMG && (unsigned)gc < (unsigned)(IMG - 3))
      v = *reinterpret_cast<const float4*>(&x[(long long)gr * IMG + gc]);
    vbuf[i] = v;
    laddr[i] = ok ? (r * LDS_STRIDE + q * 4) : -1;
  }
#pragma unroll
  for (int i = 0; i < 10; ++i)
    if (laddr[i] >= 0) *reinterpret_cast<float4*>(&lds[laddr[i]]) = vbuf[i];
  __syncthreads();

  // ---- compute: 4 wide x 2 tall per thread ----
  const int tx = t & 15;
  const int ty = t >> 4;
  float acc[2][4];
#pragma unroll
  for (int y = 0; y < 2; ++y)
#pragma unroll
    for (int xx = 0; xx < 4; ++xx) acc[y][xx] = bv;

#pragma unroll
  for (int j = 0; j < 9; ++j) {
    const int li = 4 * ty + j;
    const int xr = (li >> 2) & 7;
    float rbuf[16];
#pragma unroll
    for (int q = 0; q < 4; ++q) {
      const int c = 2 * tx + q;
      const int lq = (c < 32) ? (c ^ xr) : c;  // matches write-side swizzle
      const float4 v =
          *reinterpret_cast<const float4*>(&lds[li * LDS_STRIDE + lq * 4]);
      rbuf[4 * q + 0] = v.x;
      rbuf[4 * q + 1] = v.y;
      rbuf[4 * q + 2] = v.z;
      rbuf[4 * q + 3] = v.w;
    }
    // rbuf[i] = input col (8*tx + i) relative to g0c4; needed cols are
    // 8*tx + 2*xx + kw + 1  (the -3 pad vs -4 aligned base => +1 shift)
#pragma unroll
    for (int y = 0; y < 2; ++y) {
      const int kh = j - 2 * y;
      if (kh >= 0 && kh <= 6) {
#pragma unroll
        for (int xx = 0; xx < 4; ++xx)
#pragma unroll
          for (int kw = 0; kw < 7; ++kw)
            acc[y][xx] = fmaf(rbuf[2 * xx + kw + 1], wv[kh * 7 + kw], acc[y][xx]);
      }
    }
  }

  // ---- store: 2 x global_store_dwordx4 ----
  const int ox = tile_x + 4 * tx;
  const int oy = tile_y + 2 * ty;
#pragma unroll
  for (int y = 0; y < 2; ++y) {
    float4 v = make_float4(acc[y][0], acc[y][1], acc[y][2], acc[y][3]);
    *reinterpret_cast<float4*>(&out[(long long)(oy + y) * OUTW + ox]) = v;
  }
}

extern "C" void kernel_launch(void* const* d_in, const int* in_sizes, int n_in,
                              void* d_out, int out_size, void* d_ws, size_t ws_size,
                              hipStream_t stream) {
  const float* x = (const float*)d_in[0];
  const float* w = (const float*)d_in[1];
  const float* b = (const float*)d_in[2];
  float* out = (float*)d_out;
  dim3 grid(OUTW / TILE_W, OUTW / TILE_H);  // 64 x 128
  conv7x7_s2<<<grid, dim3(THREADS), 0, stream>>>(x, w, b, out);
}

// Round 3
// 73.570 us; speedup vs baseline: 3.0068x; 1.0034x over previous
//
#include <hip/hip_runtime.h>

// Conv2d 7x7, stride 2, pad 3, 1ch, 8192x8192 fp32 -> 4096x4096 fp32.
// 64x32 output tile / 256-thread block, 4x2 outputs per thread.
// Interior blocks: async global_load_lds (16B) staging, LDS chunk-linear,
// swizzle applied via pre-swizzled GLOBAL source address (m173 pattern).
// Edge blocks: register staging with bounds checks.
// Read side: XOR-swizzled ds_read_b128, conflict-free.

#define THREADS 256
#define TILE_W 64
#define TILE_H 32
#define IN_H 69            // TILE_H*2 + 5
#define CHUNKS 34          // float4 chunks per LDS row
#define LDS_STRIDE (CHUNKS * 4)
#define NSLOT (IN_H * CHUNKS)   // 2346
#define NSLOT_PAD 2560          // 10 rounds x 256 threads; 40 KB LDS
#define IMG 8192
#define OUTW 4096

typedef __attribute__((address_space(1))) const void global_cv;
typedef __attribute__((address_space(3))) void lds_v;

__global__ __launch_bounds__(THREADS, 4)
void conv7x7_s2(const float* __restrict__ x, const float* __restrict__ wgt,
                const float* __restrict__ bias, float* __restrict__ out) {
  __shared__ __align__(16) float lds[NSLOT_PAD * 4];
  const int t = threadIdx.x;
  const int tile_x = blockIdx.x * TILE_W;
  const int tile_y = blockIdx.y * TILE_H;
  const int g0c4 = tile_x * 2 - 4;  // aligned input col of LDS chunk 0
  const int g0r = tile_y * 2 - 3;   // input row of LDS row 0

  float wv[49];
#pragma unroll
  for (int i = 0; i < 49; ++i) wv[i] = wgt[i];
  const float bv = bias[0];

  const bool interior = (blockIdx.x >= 1) & (blockIdx.x <= 62) &
                        (blockIdx.y >= 1) & (blockIdx.y <= 126);

  if (interior) {
    // ---- async staging: HBM -> LDS direct, no bounds checks ----
    const float* xb = x + (long long)g0r * IMG + g0c4;
#pragma unroll
    for (int i = 0; i < 10; ++i) {
      const int s = t + THREADS * i;        // linear LDS chunk index
      const int r = s / CHUNKS;
      const int q = s - r * CHUNKS;
      const int xr = (r >> 2) & 7;
      const int src = (q < 32) ? (q ^ xr) : q;  // pre-swizzled global chunk
      const float* gp = xb + r * IMG + 4 * src;
      if (i == 9 && s >= NSLOT) gp = x;     // pad lanes: any valid address
      __builtin_amdgcn_global_load_lds((global_cv*)gp, (lds_v*)&lds[s * 4],
                                       16, 0, 0);
    }
  } else {
    // ---- edge path: register staging with bounds checks ----
    float4 vbuf[10];
    int laddr[10];
#pragma unroll
    for (int i = 0; i < 10; ++i) {
      const int s = t + THREADS * i;
      const bool ok = (s < NSLOT);
      const int r = s / CHUNKS;
      const int q = s - r * CHUNKS;
      const int xr = (r >> 2) & 7;
      const int src = (q < 32) ? (q ^ xr) : q;
      const int gr = g0r + r;
      const int gc = g0c4 + 4 * src;
      float4 v = make_float4(0.f, 0.f, 0.f, 0.f);
      if (ok && (unsigned)gr < (unsigned)IMG && (unsigned)gc < (unsigned)(IMG - 3))
        v = *reinterpret_cast<const float4*>(&x[(long long)gr * IMG + gc]);
      vbuf[i] = v;
      laddr[i] = ok ? s * 4 : -1;
    }
#pragma unroll
    for (int i = 0; i < 10; ++i)
      if (laddr[i] >= 0) *reinterpret_cast<float4*>(&lds[laddr[i]]) = vbuf[i];
  }
  __syncthreads();   // drains vmcnt (global_load_lds) + lgkmcnt

  // ---- compute: 4 wide x 2 tall per thread ----
  const int tx = t & 15;
  const int ty = t >> 4;
  float acc[2][4];
#pragma unroll
  for (int y = 0; y < 2; ++y)
#pragma unroll
    for (int xx = 0; xx < 4; ++xx) acc[y][xx] = bv;

#pragma unroll
  for (int j = 0; j < 9; ++j) {
    const int li = 4 * ty + j;
    const int xr = (li >> 2) & 7;
    float rbuf[16];
#pragma unroll
    for (int q = 0; q < 4; ++q) {
      const int c = 2 * tx + q;
      const int lq = (c < 32) ? (c ^ xr) : c;
      const float4 v =
          *reinterpret_cast<const float4*>(&lds[li * LDS_STRIDE + lq * 4]);
      rbuf[4 * q + 0] = v.x;
      rbuf[4 * q + 1] = v.y;
      rbuf[4 * q + 2] = v.z;
      rbuf[4 * q + 3] = v.w;
    }
    // rbuf[i] = input col (8*tx + i) rel. to g0c4; needed col = 8tx+2xx+kw+1
#pragma unroll
    for (int y = 0; y < 2; ++y) {
      const int kh = j - 2 * y;
      if (kh >= 0 && kh <= 6) {
#pragma unroll
        for (int xx = 0; xx < 4; ++xx)
#pragma unroll
          for (int kw = 0; kw < 7; ++kw)
            acc[y][xx] = fmaf(rbuf[2 * xx + kw + 1], wv[kh * 7 + kw], acc[y][xx]);
      }
    }
  }

  // ---- store: 2 x global_store_dwordx4 ----
  const int ox = tile_x + 4 * tx;
  const int oy = tile_y + 2 * ty;
#pragma unroll
  for (int y = 0; y < 2; ++y) {
    float4 v = make_float4(acc[y][0], acc[y][1], acc[y][2], acc[y][3]);
    *reinterpret_cast<float4*>(&out[(long long)(oy + y) * OUTW + ox]) = v;
  }
}

extern "C" void kernel_launch(void* const* d_in, const int* in_sizes, int n_in,
                              void* d_out, int out_size, void* d_ws, size_t ws_size,
                              hipStream_t stream) {
  const float* x = (const float*)d_in[0];
  const float* w = (const float*)d_in[1];
  const float* b = (const float*)d_in[2];
  float* out = (float*)d_out;
  dim3 grid(OUTW / TILE_W, OUTW / TILE_H);  // 64 x 128
  conv7x7_s2<<<grid, dim3(THREADS), 0, stream>>>(x, w, b, out);
}